// Round 2
// baseline (3257.996 us; speedup 1.0000x reference)
//
#include <hip/hip_runtime.h>
#include <hip/hip_bf16.h>
#include <math.h>

#define NDRUG 500
#define NCELL 500
#define NGENE 9000
#define NN    10000
#define H1    256
#define CH    128
#define HEADS 4
#define DOUT  512      /* HEADS*CH */
#define EE    200000
#define E2T   210000   /* EE + NN self loops */
#define BSZ   8192
#define SLOPE 0.2f
#define LNEPS 1e-5f
#define HASH_SIZE (1u<<19)
#define HASH_MASK (HASH_SIZE-1u)

// ---------------- fp32 tiled GEMM: C[M,Nc] = A[M,K] @ B[Nc,K]^T (+bias) ----------------
__global__ __launch_bounds__(256) void gemm_nt(const float* __restrict__ A,
                                               const float* __restrict__ B,
                                               const float* __restrict__ bias,
                                               float* __restrict__ C,
                                               int M, int Nc, int K) {
  __shared__ float As[16][68];   // transposed tiles: [k][row], 68 pad keeps float4 align (272B = 17*16)
  __shared__ float Bs[16][68];
  int tid = threadIdx.x;
  int tx = tid & 15, ty = tid >> 4;
  int bm = blockIdx.x * 64, bn = blockIdx.y * 64;
  float acc[4][4] = {};
  for (int k0 = 0; k0 < K; k0 += 16) {
#pragma unroll
    for (int i = 0; i < 4; ++i) {
      int idx = tid + i * 256;          // 0..1023
      int r = idx >> 4, c = idx & 15;   // r 0..63, c 0..15
      int gr = bm + r, gc = k0 + c;
      As[c][r] = (gr < M && gc < K) ? A[(size_t)gr * K + gc] : 0.f;
      int hr = bn + r;
      Bs[c][r] = (hr < Nc && gc < K) ? B[(size_t)hr * K + gc] : 0.f;
    }
    __syncthreads();
#pragma unroll
    for (int k = 0; k < 16; ++k) {
      float4 av = *(const float4*)&As[k][ty * 4];
      float4 bv = *(const float4*)&Bs[k][tx * 4];
      float a[4] = {av.x, av.y, av.z, av.w};
      float b[4] = {bv.x, bv.y, bv.z, bv.w};
#pragma unroll
      for (int i = 0; i < 4; ++i)
#pragma unroll
        for (int j = 0; j < 4; ++j) acc[i][j] += a[i] * b[j];
    }
    __syncthreads();
  }
#pragma unroll
  for (int i = 0; i < 4; ++i) {
    int r = bm + ty * 4 + i;
    if (r >= M) continue;
#pragma unroll
    for (int j = 0; j < 4; ++j) {
      int c = bn + tx * 4 + j;
      if (c < Nc) C[(size_t)r * Nc + c] = acc[i][j] + (bias ? bias[c] : 0.f);
    }
  }
}

// ---------------- graph prep ----------------
__global__ void k_deg(const int* __restrict__ dst, const float* __restrict__ ea,
                      float* __restrict__ cnt, float* __restrict__ lsum) {
  int e = blockIdx.x * blockDim.x + threadIdx.x;
  if (e < EE) {
    atomicAdd(&cnt[dst[e]], 1.f);
    atomicAdd(&lsum[dst[e]], ea[e]);
  }
}

__global__ void k_loopattr(const float* cnt, const float* lsum, float* lattr) {
  int n = blockIdx.x * blockDim.x + threadIdx.x;
  if (n < NN) lattr[n] = lsum[n] / fmaxf(cnt[n], 1.f);
}

// single-block exclusive scan of deg2[n] = cnt[n]+1 -> off[0..NN]
__global__ void k_scan(const float* __restrict__ cnt, unsigned* __restrict__ off) {
  __shared__ unsigned wsum[4];
  __shared__ unsigned carry;
  if (threadIdx.x == 0) carry = 0;
  __syncthreads();
  int lane = threadIdx.x & 63, wid = threadIdx.x >> 6;
  for (int base = 0; base < NN; base += 256) {
    int n = base + (int)threadIdx.x;
    unsigned v = (n < NN) ? ((unsigned)cnt[n] + 1u) : 0u;
    unsigned x = v;
#pragma unroll
    for (int d = 1; d < 64; d <<= 1) {
      unsigned y = __shfl_up(x, d, 64);
      if (lane >= d) x += y;
    }
    if (lane == 63) wsum[wid] = x;
    __syncthreads();
    unsigned wpre = 0;
    for (int w = 0; w < wid; ++w) wpre += wsum[w];
    if (n < NN) off[n] = carry + wpre + x - v;
    unsigned total = wsum[0] + wsum[1] + wsum[2] + wsum[3];
    __syncthreads();
    if (threadIdx.x == 0) carry += total;
    __syncthreads();
  }
  if (threadIdx.x == 0) off[NN] = carry;
}

__global__ void k_fill(const int* __restrict__ dst, const unsigned* __restrict__ off,
                       unsigned* __restrict__ cur, unsigned* __restrict__ eid) {
  int e2 = blockIdx.x * blockDim.x + threadIdx.x;
  if (e2 >= E2T) return;
  int d = (e2 < EE) ? dst[e2] : (e2 - EE);
  unsigned pos = atomicAdd(&cur[d], 1u);
  eid[off[d] + pos] = (unsigned)e2;
}

// ---------------- GAT edge kernels ----------------
__global__ void k_ledgedot(const float* __restrict__ ledge, const float* __restrict__ aedge,
                           float* __restrict__ ld) {
  __shared__ float red[512];
  red[threadIdx.x] = ledge[threadIdx.x] * aedge[threadIdx.x];
  __syncthreads();
  for (int s = 64; s; s >>= 1) {
    if ((threadIdx.x & 127) < s) red[threadIdx.x] += red[threadIdx.x + s];
    __syncthreads();
  }
  if ((threadIdx.x & 127) == 0) ld[threadIdx.x >> 7] = red[threadIdx.x];
}

__global__ void k_aldot(const float* __restrict__ xh, const float* __restrict__ asrc,
                        const float* __restrict__ adst, float* __restrict__ als,
                        float* __restrict__ ald) {
  int wg = blockIdx.x * 4 + ((int)threadIdx.x >> 6);  // (n,h) per wave
  int n = wg >> 2, h = wg & 3;
  int lane = threadIdx.x & 63;
  const float* xp = xh + (size_t)n * DOUT + h * CH;
  float a0 = xp[lane], a1 = xp[lane + 64];
  float s = a0 * asrc[h * CH + lane] + a1 * asrc[h * CH + lane + 64];
  float d = a0 * adst[h * CH + lane] + a1 * adst[h * CH + lane + 64];
#pragma unroll
  for (int o = 32; o; o >>= 1) {
    s += __shfl_down(s, o, 64);
    d += __shfl_down(d, o, 64);
  }
  if (lane == 0) { als[n * 4 + h] = s; ald[n * 4 + h] = d; }
}

__device__ inline float dec_ord(unsigned u) {
  return __uint_as_float((u & 0x80000000u) ? (u & 0x7FFFFFFFu) : ~u);
}

__global__ void k_alpha(const int* __restrict__ src, const int* __restrict__ dst,
                        const float* __restrict__ ea, const float* __restrict__ lattr,
                        const float* __restrict__ als, const float* __restrict__ ald,
                        const float* __restrict__ ld, float* __restrict__ alpha,
                        unsigned* __restrict__ mmax) {
  int idx = blockIdx.x * blockDim.x + threadIdx.x;
  if (idx >= E2T * HEADS) return;
  int e2 = idx >> 2, h = idx & 3;
  int s, d; float eav;
  if (e2 < EE) { s = src[e2]; d = dst[e2]; eav = ea[e2]; }
  else         { s = d = e2 - EE; eav = lattr[s]; }
  float v = als[s * 4 + h] + ald[d * 4 + h] + eav * ld[h];
  v = v > 0.f ? v : SLOPE * v;
  alpha[idx] = v;
  unsigned enc = __float_as_uint(v);
  enc = (enc & 0x80000000u) ? ~enc : (enc | 0x80000000u);
  atomicMax(&mmax[d * 4 + h], enc);
}

__global__ void k_expsum(const int* __restrict__ dst, float* __restrict__ alpha,
                         const unsigned* __restrict__ mmax, float* __restrict__ ssum) {
  int idx = blockIdx.x * blockDim.x + threadIdx.x;
  if (idx >= E2T * HEADS) return;
  int e2 = idx >> 2, h = idx & 3;
  int d = (e2 < EE) ? dst[e2] : (e2 - EE);
  float m = dec_ord(mmax[d * 4 + h]);
  float v = expf(alpha[idx] - m);
  alpha[idx] = v;
  atomicAdd(&ssum[d * 4 + h], v);
}

__global__ void k_fin(const int* __restrict__ dst, float* __restrict__ alpha,
                      const float* __restrict__ ssum, float* __restrict__ amean) {
  int e2 = blockIdx.x * blockDim.x + threadIdx.x;
  if (e2 >= E2T) return;
  int d = (e2 < EE) ? dst[e2] : (e2 - EE);
  float t = 0.f;
#pragma unroll
  for (int h = 0; h < 4; ++h) {
    float a = alpha[e2 * 4 + h] / (ssum[d * 4 + h] + 1e-16f);
    alpha[e2 * 4 + h] = a;
    t += a;
  }
  amean[e2] = t * 0.25f;
}

__global__ void k_agg(const unsigned* __restrict__ off, const unsigned* __restrict__ eid,
                      const int* __restrict__ src, const float* __restrict__ xh,
                      const float* __restrict__ alpha, const float* __restrict__ bias,
                      float* __restrict__ outp) {
  int n = blockIdx.x;
  int c0 = threadIdx.x, c1 = threadIdx.x + 256;
  int h0 = c0 >> 7, h1 = c1 >> 7;
  float a0 = 0.f, a1 = 0.f;
  unsigned b0 = off[n], b1 = off[n + 1];
  for (unsigned i = b0; i < b1; ++i) {
    unsigned e2 = eid[i];
    int s = (e2 < EE) ? src[e2] : (int)(e2 - EE);
    const float* xp = xh + (size_t)s * DOUT;
    a0 += xp[c0] * alpha[e2 * 4 + h0];
    a1 += xp[c1] * alpha[e2 * 4 + h1];
  }
  outp[(size_t)n * DOUT + c0] = a0 + bias[c0];
  outp[(size_t)n * DOUT + c1] = a1 + bias[c1];
}

__device__ inline float blk_reduce(float v, float* lds) {
  int lane = threadIdx.x & 63, wid = threadIdx.x >> 6;
#pragma unroll
  for (int o = 32; o; o >>= 1) v += __shfl_down(v, o, 64);
  if (lane == 0) lds[wid] = v;
  __syncthreads();
  float r = lds[0] + lds[1] + lds[2] + lds[3];
  __syncthreads();
  return r;
}

__global__ void k_lnrelu(const float* __restrict__ in, const float* __restrict__ g,
                         const float* __restrict__ b, float* __restrict__ outp) {
  __shared__ float lds[4];
  int n = blockIdx.x;
  const float* row = in + (size_t)n * DOUT;
  float v0 = row[threadIdx.x], v1 = row[threadIdx.x + 256];
  float mu = blk_reduce(v0 + v1, lds) * (1.f / 512.f);
  float d0 = v0 - mu, d1 = v1 - mu;
  float var = blk_reduce(d0 * d0 + d1 * d1, lds) * (1.f / 512.f);
  float r = rsqrtf(var + LNEPS);
  int c0 = threadIdx.x, c1 = threadIdx.x + 256;
  float y0 = d0 * r * g[c0] + b[c0];
  float y1 = d1 * r * g[c1] + b[c1];
  outp[(size_t)n * DOUT + c0] = y0 > 0.f ? y0 : 0.f;
  outp[(size_t)n * DOUT + c1] = y1 > 0.f ? y1 : 0.f;
}

// ---------------- prediction head ----------------
__global__ void k_pred(const float* __restrict__ x2, const int* __restrict__ idxd,
                       const int* __restrict__ idxc, const float* __restrict__ w,
                       const float* __restrict__ bb, float* __restrict__ pred) {
  int bidx = blockIdx.x * 4 + ((int)threadIdx.x >> 6);
  int lane = threadIdx.x & 63;
  const float* xd = x2 + (size_t)idxd[bidx] * DOUT;
  const float* xc = x2 + (size_t)idxc[bidx] * DOUT;
  float acc = 0.f;
  for (int k = lane; k < DOUT; k += 64) acc += xd[k] * w[k] + xc[k] * w[DOUT + k];
#pragma unroll
  for (int o = 32; o; o >>= 1) acc += __shfl_down(acc, o, 64);
  if (lane == 0) pred[bidx] = acc + bb[0];
}

// ---------------- last-wins duplicate resolution + att scatter ----------------
__device__ inline unsigned hash32(unsigned x) {
  x ^= x >> 16; x *= 0x7feb352dU; x ^= x >> 15; x *= 0x846ca68bU; x ^= x >> 16;
  return x;
}

__global__ void k_hins(const int* __restrict__ src, const int* __restrict__ dst,
                       unsigned* __restrict__ keys, unsigned* __restrict__ vals) {
  int e2 = blockIdx.x * blockDim.x + threadIdx.x;
  if (e2 >= E2T) return;
  int s = (e2 < EE) ? src[e2] : (e2 - EE);
  int d = (e2 < EE) ? dst[e2] : (e2 - EE);
  unsigned pair = (unsigned)s * 10000u + (unsigned)d;
  unsigned slot = hash32(pair) & HASH_MASK;
  while (true) {
    unsigned prev = atomicCAS(&keys[slot], 0xFFFFFFFFu, pair);
    if (prev == 0xFFFFFFFFu || prev == pair) {
      atomicMax(&vals[slot], (unsigned)e2);
      break;
    }
    slot = (slot + 1u) & HASH_MASK;
  }
}

__global__ void k_attw(const int* __restrict__ src, const int* __restrict__ dst,
                       const unsigned* __restrict__ keys, const unsigned* __restrict__ vals,
                       const float* __restrict__ am0, const float* __restrict__ am1,
                       float* __restrict__ att) {
  int e2 = blockIdx.x * blockDim.x + threadIdx.x;
  if (e2 >= E2T) return;
  int s = (e2 < EE) ? src[e2] : (e2 - EE);
  int d = (e2 < EE) ? dst[e2] : (e2 - EE);
  unsigned pair = (unsigned)s * 10000u + (unsigned)d;
  unsigned slot = hash32(pair) & HASH_MASK;
  while (keys[slot] != pair) slot = (slot + 1u) & HASH_MASK;
  if (vals[slot] == (unsigned)e2) att[(size_t)s * NN + d] = am0[e2] + am1[e2];
}

// ---------------- host-side layer driver ----------------
static void run_layer(const float* x_in, int din,
                      const float* lin, const float* asrc, const float* adst,
                      const float* ledge, const float* aedge, const float* bias,
                      const float* lng, const float* lnb,
                      const int* src, const int* dst, const float* eattr, const float* lattr,
                      float* xh, float* ago, float* x_out,
                      float* als, float* ald, float* alpha, float* ssum, unsigned* mmax,
                      float* ldot, float* amean,
                      const unsigned* off, const unsigned* eid2, hipStream_t stream) {
  hipMemsetAsync(ssum, 0, NN * HEADS * sizeof(float), stream);
  hipMemsetAsync(mmax, 0, NN * HEADS * sizeof(unsigned), stream);
  gemm_nt<<<dim3((NN + 63) / 64, DOUT / 64), 256, 0, stream>>>(x_in, lin, nullptr, xh, NN, DOUT, din);
  k_ledgedot<<<1, 512, 0, stream>>>(ledge, aedge, ldot);
  k_aldot<<<NN * HEADS / 4, 256, 0, stream>>>(xh, asrc, adst, als, ald);
  int ge = (E2T * HEADS + 255) / 256;
  k_alpha<<<ge, 256, 0, stream>>>(src, dst, eattr, lattr, als, ald, ldot, alpha, mmax);
  k_expsum<<<ge, 256, 0, stream>>>(dst, alpha, mmax, ssum);
  k_fin<<<(E2T + 255) / 256, 256, 0, stream>>>(dst, alpha, ssum, amean);
  k_agg<<<NN, 256, 0, stream>>>(off, eid2, src, xh, alpha, bias, ago);
  k_lnrelu<<<NN, 256, 0, stream>>>(ago, lng, lnb, x_out);
}

extern "C" void kernel_launch(void* const* d_in, const int* in_sizes, int n_in,
                              void* d_out, int out_size, void* d_ws, size_t ws_size,
                              hipStream_t stream) {
  const float* drug  = (const float*)d_in[0];
  const float* cell  = (const float*)d_in[1];
  const float* gene  = (const float*)d_in[2];
  const int*   eidx  = (const int*)d_in[3];
  const float* eattr = (const float*)d_in[4];
  const int*   idxd  = (const int*)d_in[5];
  const int*   idxc  = (const int*)d_in[6];
  const float* Wd = (const float*)d_in[7];   const float* bd = (const float*)d_in[8];
  const float* Wc = (const float*)d_in[9];   const float* bc = (const float*)d_in[10];
  const float* Wg = (const float*)d_in[11];  const float* bg = (const float*)d_in[12];
  const float* l0_lin  = (const float*)d_in[13];
  const float* l0_asrc = (const float*)d_in[14];
  const float* l0_adst = (const float*)d_in[15];
  const float* l0_ledge= (const float*)d_in[16];
  const float* l0_aedge= (const float*)d_in[17];
  const float* l0_bias = (const float*)d_in[18];
  const float* l0_lng  = (const float*)d_in[19];
  const float* l0_lnb  = (const float*)d_in[20];
  const float* l1_lin  = (const float*)d_in[21];
  const float* l1_asrc = (const float*)d_in[22];
  const float* l1_adst = (const float*)d_in[23];
  const float* l1_ledge= (const float*)d_in[24];
  const float* l1_aedge= (const float*)d_in[25];
  const float* l1_bias = (const float*)d_in[26];
  const float* l1_lng  = (const float*)d_in[27];
  const float* l1_lnb  = (const float*)d_in[28];
  const float* mlp_w   = (const float*)d_in[29];
  const float* mlp_b   = (const float*)d_in[30];
  float* out = (float*)d_out;

  const int* src = eidx;
  const int* dst = eidx + EE;

  char* wptr = (char*)d_ws;
  auto alloc = [&](size_t elems) -> char* {
    char* p = wptr;
    wptr += ((elems * 4 + 255) / 256) * 256;
    return p;
  };
  float* x0    = (float*)alloc((size_t)NN * H1);
  float* xh    = (float*)alloc((size_t)NN * DOUT);
  float* ago   = (float*)alloc((size_t)NN * DOUT);
  float* xln   = (float*)alloc((size_t)NN * DOUT);
  float* alpha = (float*)alloc((size_t)E2T * HEADS);
  float* am0   = (float*)alloc(E2T);
  float* am1   = (float*)alloc(E2T);
  float* als   = (float*)alloc(NN * HEADS);
  float* ald   = (float*)alloc(NN * HEADS);
  float* cntf  = (float*)alloc(NN);
  float* lsum  = (float*)alloc(NN);
  float* lattr = (float*)alloc(NN);
  float* ssum  = (float*)alloc(NN * HEADS);
  float* ldot  = (float*)alloc(64);
  unsigned* mmax  = (unsigned*)alloc(NN * HEADS);
  unsigned* off   = (unsigned*)alloc(NN + 1);
  unsigned* cur   = (unsigned*)alloc(NN);
  unsigned* eid2  = (unsigned*)alloc(E2T);
  unsigned* hkeys = (unsigned*)alloc(HASH_SIZE);
  unsigned* hvals = (unsigned*)alloc(HASH_SIZE);

  // init (d_out / d_ws are poisoned before every timed launch)
  hipMemsetAsync(d_out, 0, (size_t)out_size * sizeof(float), stream);
  hipMemsetAsync(cntf, 0, NN * sizeof(float), stream);
  hipMemsetAsync(lsum, 0, NN * sizeof(float), stream);
  hipMemsetAsync(cur, 0, NN * sizeof(unsigned), stream);
  hipMemsetAsync(hkeys, 0xFF, HASH_SIZE * sizeof(unsigned), stream);
  hipMemsetAsync(hvals, 0, HASH_SIZE * sizeof(unsigned), stream);

  // graph prep
  k_deg<<<(EE + 255) / 256, 256, 0, stream>>>(dst, eattr, cntf, lsum);
  k_loopattr<<<(NN + 255) / 256, 256, 0, stream>>>(cntf, lsum, lattr);
  k_scan<<<1, 256, 0, stream>>>(cntf, off);
  k_fill<<<(E2T + 255) / 256, 256, 0, stream>>>(dst, off, cur, eid2);

  // input projections -> x0 [NN, 256]
  gemm_nt<<<dim3(8, 4), 256, 0, stream>>>(drug, Wd, bd, x0, NDRUG, H1, NDRUG);
  gemm_nt<<<dim3(8, 4), 256, 0, stream>>>(cell, Wc, bc, x0 + (size_t)NDRUG * H1, NCELL, H1, NCELL);
  gemm_nt<<<dim3(141, 4), 256, 0, stream>>>(gene, Wg, bg, x0 + (size_t)(NDRUG + NCELL) * H1, NGENE, H1, NGENE);

  // GAT layers
  run_layer(x0, H1, l0_lin, l0_asrc, l0_adst, l0_ledge, l0_aedge, l0_bias, l0_lng, l0_lnb,
            src, dst, eattr, lattr, xh, ago, xln, als, ald, alpha, ssum, mmax, ldot, am0,
            off, eid2, stream);
  run_layer(xln, DOUT, l1_lin, l1_asrc, l1_adst, l1_ledge, l1_aedge, l1_bias, l1_lng, l1_lnb,
            src, dst, eattr, lattr, xh, ago, xln, als, ald, alpha, ssum, mmax, ldot, am1,
            off, eid2, stream);

  // prediction head
  k_pred<<<BSZ / 4, 256, 0, stream>>>(xln, idxd, idxc, mlp_w, mlp_b, out);

  // attention matrix (last-wins on duplicate (src,dst) pairs)
  k_hins<<<(E2T + 255) / 256, 256, 0, stream>>>(src, dst, hkeys, hvals);
  k_attw<<<(E2T + 255) / 256, 256, 0, stream>>>(src, dst, hkeys, hvals, am0, am1, out + BSZ);
}